// Round 17
// baseline (16571.349 us; speedup 1.0000x reference)
//
#include <hip/hip_runtime.h>

typedef unsigned int u32;
typedef unsigned long long u64;

#define N_PTS 16384
#define N_S   8192
#define NB    10
#define CHID  64
#define COUT  128
#define R2    0.0625f
#define NCELL 4096

// ======================= sort: morton counting sort =======================
__global__ void zero_hist(int* __restrict__ hist) {
  hist[blockIdx.x * 256 + threadIdx.x] = 0;
}

__device__ __forceinline__ u32 spread3(u32 v) {  // 4 bits -> every 3rd bit
  return (v & 1u) | ((v & 2u) << 2) | ((v & 4u) << 4) | ((v & 8u) << 6);
}

__global__ void cell_kernel(const float* __restrict__ pos, int* __restrict__ cellid,
                            int* __restrict__ hist) {
  int i = blockIdx.x * 256 + threadIdx.x;
  float x = pos[3 * i], y = pos[3 * i + 1], z = pos[3 * i + 2];
  u32 ix = (u32)(x * 16.0f); if (ix > 15u) ix = 15u;
  u32 iy = (u32)(y * 16.0f); if (iy > 15u) iy = 15u;
  u32 iz = (u32)(z * 16.0f); if (iz > 15u) iz = 15u;
  u32 c = spread3(ix) | (spread3(iy) << 1) | (spread3(iz) << 2);
  cellid[i] = (int)c;
  atomicAdd(&hist[c], 1);
}

__global__ __launch_bounds__(1024) void scan_kernel(const int* __restrict__ hist,
                                                    int* __restrict__ base) {
  __shared__ int sp[1024];
  int t = threadIdx.x;
  int h0 = hist[4 * t], h1 = hist[4 * t + 1], h2 = hist[4 * t + 2], h3 = hist[4 * t + 3];
  int s = h0 + h1 + h2 + h3;
  int acc = s;
  sp[t] = s;
  __syncthreads();
  for (int off = 1; off < 1024; off <<= 1) {
    int v = (t >= off) ? sp[t - off] : 0;
    __syncthreads();
    acc += v;
    sp[t] = acc;
    __syncthreads();
  }
  int excl = acc - s;
  base[4 * t + 0] = excl;
  base[4 * t + 1] = excl + h0;
  base[4 * t + 2] = excl + h0 + h1;
  base[4 * t + 3] = excl + h0 + h1 + h2;
}

__global__ void scatter_kernel(const float* __restrict__ pos, const int* __restrict__ cellid,
                               int* __restrict__ base, float* __restrict__ xs,
                               float* __restrict__ ys, float* __restrict__ zs,
                               int* __restrict__ oid) {
  int i = blockIdx.x * 256 + threadIdx.x;
  int c = cellid[i];
  int d = atomicAdd(&base[c], 1);
  xs[d] = pos[3 * i]; ys[d] = pos[3 * i + 1]; zs[d] = pos[3 * i + 2];
  oid[d] = i;
}

// ======================= FPS: zero-memory loop (512thr x 32ppt) ================
// R16 post-mortem: best-run FETCH 134MB = 16KB/iter = the active wave's body
// x-loads going to HBM every iter (co-tenants evict xs from L2) -> ~900cyc on
// the active wave's serial path. Fix: x in registers (loop-invariant). At
// 512thr/waves_per_eu(2,2) the grant is 128 (R8 measured); need x32+md32+
// lkp16+bb6+temps ~= 106 < 128. Body = LDS-only. Winner cx recovered on-chip:
// 31-cndmask tree over own x regs (J=ckey&31) + own-cell yz read, exported as
// float4 s_wc pre-barrier (parity forwarding, no extra barrier - R13 lesson).
#define FPS_T 512
#define PPT   32

// OP(G, J0,J1,J2,J3, PA,PB): float4 group G covers points 4G..4G+3, lk pairs PA,PB
#define G4_LIST(OP) OP(0,0,1,2,3,0,1)       OP(1,4,5,6,7,2,3) \
                    OP(2,8,9,10,11,4,5)     OP(3,12,13,14,15,6,7) \
                    OP(4,16,17,18,19,8,9)   OP(5,20,21,22,23,10,11) \
                    OP(6,24,25,26,27,12,13) OP(7,28,29,30,31,14,15)
// OP(PA, Jeven, Jodd)
#define PAIR_LIST(OP) OP(0,0,1) OP(1,2,3) OP(2,4,5) OP(3,6,7) OP(4,8,9) \
                      OP(5,10,11) OP(6,12,13) OP(7,14,15) OP(8,16,17) OP(9,18,19) \
                      OP(10,20,21) OP(11,22,23) OP(12,24,25) OP(13,26,27) \
                      OP(14,28,29) OP(15,30,31)

// u64 max via positive-double max (keys < 2^60 -> exponent never all-ones, no
// NaN/inf patterns; positive doubles order == bit order).
__device__ __forceinline__ u64 u64fmax(u64 a, u64 b) {
  double ad = __longlong_as_double((long long)a);
  double bd = __longlong_as_double((long long)b);
  return (u64)(long long)__double_as_longlong(fmax(ad, bd));
}

template <int CTRL, int RM>
__device__ __forceinline__ u64 dppmax(u64 cur) {
  int slo = __builtin_amdgcn_update_dpp(0, (int)(u32)cur, CTRL, RM, 0xf, false);
  int shi = __builtin_amdgcn_update_dpp(0, (int)(u32)(cur >> 32), CTRL, RM, 0xf, false);
  u64 o = ((u64)(u32)shi << 32) | (u32)slo;
  return u64fmax(o, cur);
}

__global__ __attribute__((amdgpu_flat_work_group_size(512, 512)))
__attribute__((amdgpu_waves_per_eu(2, 2)))
void fps_kernel(const float* __restrict__ pos,
                const float* __restrict__ xs,
                const float* __restrict__ ys,
                const float* __restrict__ zs,
                const int* __restrict__ oidv,
                int* __restrict__ idx_out) {
  __shared__ float2 s_yz[PPT * FPS_T];   // [j][t] interleaved (y,z): 128 KB
  __shared__ u64    s_wkey[2][8];        // parity double-buffer
  __shared__ float4 s_wc[2][8];          // winner (x,y,z) per wave, parity
  const int t = threadIdx.x;
  const int wv = t >> 6;
  const int base0 = t * PPT;
  const float4* __restrict__ xv = (const float4*)(xs + base0);
  const float4* __restrict__ yv = (const float4*)(ys + base0);
  const float4* __restrict__ zv = (const float4*)(zs + base0);
  const int4*   __restrict__ ov = (const int4*)(oidv + base0);

  // ---- per-point register state: x (loop-invariant!) + md + packed tie keys
#define DECLG(G, J0, J1, J2, J3, PA, PB) \
  float x##J0, x##J1, x##J2, x##J3, md##J0, md##J1, md##J2, md##J3; \
  u32 lkp##PA, lkp##PB;
  G4_LIST(DECLG)
#undef DECLG

  float bnx = 3.4e38f, bxx = -3.4e38f, bny = 3.4e38f, bxy = -3.4e38f,
        bnz = 3.4e38f, bxz = -3.4e38f;
#define INIT4(G, J0, J1, J2, J3, PA, PB) { \
    float4 vx = xv[G], vy = yv[G], vz = zv[G]; int4 vo = ov[G]; \
    x##J0 = vx.x; x##J1 = vx.y; x##J2 = vx.z; x##J3 = vx.w; \
    md##J0 = 3.402823466e38f; md##J1 = 3.402823466e38f; \
    md##J2 = 3.402823466e38f; md##J3 = 3.402823466e38f; \
    s_yz[J0 * FPS_T + t] = make_float2(vy.x, vz.x); \
    s_yz[J1 * FPS_T + t] = make_float2(vy.y, vz.y); \
    s_yz[J2 * FPS_T + t] = make_float2(vy.z, vz.z); \
    s_yz[J3 * FPS_T + t] = make_float2(vy.w, vz.w); \
    lkp##PA = (16383u - (u32)vo.x) | ((16383u - (u32)vo.y) << 16); \
    lkp##PB = (16383u - (u32)vo.z) | ((16383u - (u32)vo.w) << 16); \
    bnx = fminf(bnx, fminf(fminf(vx.x, vx.y), fminf(vx.z, vx.w))); \
    bxx = fmaxf(bxx, fmaxf(fmaxf(vx.x, vx.y), fmaxf(vx.z, vx.w))); \
    bny = fminf(bny, fminf(fminf(vy.x, vy.y), fminf(vy.z, vy.w))); \
    bxy = fmaxf(bxy, fmaxf(fmaxf(vy.x, vy.y), fmaxf(vy.z, vy.w))); \
    bnz = fminf(bnz, fminf(fminf(vz.x, vz.y), fminf(vz.z, vz.w))); \
    bxz = fmaxf(bxz, fmaxf(fmaxf(vz.x, vz.y), fmaxf(vz.z, vz.w))); }
  G4_LIST(INIT4)
#undef INIT4

  // key = md_bits<<28 | (16383-oid)<<14 | sidx (60 bits). md >= 0 -> float order
  // == bit order. Lex max == numpy argmax (max md, tie -> min oid); sidx trails.
  u64 ckey = 0;
  float cmaxf = 3.402823466e38f;        // forces all-active first iteration
  float cx = pos[0], cy = pos[1], cz = pos[2];
  if (t == 0) idx_out[0] = 0;
  __syncthreads();

  for (int k = 0; k < N_S - 1; ++k) {
    // ---- prune (registers only): bbox lower bound vs chunk max-min-dist.
    // Skip-safe: if 0.99*lb2 >= cmaxf no md in this chunk can decrease (1%
    // margin >> fp32 rounding of 3-term sums) -> chunk state exactly unchanged.
    float dxl = fmaxf(fmaxf(bnx - cx, cx - bxx), 0.0f);
    float dyl = fmaxf(fmaxf(bny - cy, cy - bxy), 0.0f);
    float dzl = fmaxf(fmaxf(bnz - cz, cz - bxz), 0.0f);
    float lb2 = dxl * dxl + dyl * dyl + dzl * dzl;
    bool act = (0.99f * lb2 < cmaxf);
    const int p = k & 1;

    if (__ballot(act)) {
      if (act) {
        u64 bkA = 0, bkB = 0;   // even/odd accumulators: halves the dep chain
        // exact numpy arithmetic: per-op rounding, no FMA contraction.
        // x from registers; y,z one b64 LDS read each. ZERO global access.
#define UPD1(J, LKE, ACC) { \
        float2 yz = s_yz[J * FPS_T + t]; \
        float dx = __fsub_rn(x##J, cx); \
        float dy = __fsub_rn(yz.x, cy); \
        float dz = __fsub_rn(yz.y, cz); \
        float d2 = __fadd_rn(__fadd_rn(__fmul_rn(dx, dx), __fmul_rn(dy, dy)), __fmul_rn(dz, dz)); \
        float m = fminf(md##J, d2); md##J = m; \
        u32 mb = __float_as_uint(m); \
        u64 kj = ((u64)(mb >> 4) << 32) | ((mb << 28) | ((LKE) << 14) | (u32)(base0 + J)); \
        ACC = u64fmax(ACC, kj); }
#define UPD2(PA, JE, JO) UPD1(JE, (lkp##PA & 0xffffu), bkA) UPD1(JO, (lkp##PA >> 16), bkB)
        PAIR_LIST(UPD2)
#undef UPD2
#undef UPD1
        ckey = u64fmax(bkA, bkB);
        cmaxf = __uint_as_float((u32)(ckey >> 28));
      }
      // wave64 max via DPP (row_shr scan + row broadcasts): lane 63 = wave max.
      // Inactive lanes carry their old (still-valid) ckey.
      u64 wk = ckey;
      wk = dppmax<0x111, 0xf>(wk);   // row_shr:1
      wk = dppmax<0x112, 0xf>(wk);   // row_shr:2
      wk = dppmax<0x114, 0xf>(wk);   // row_shr:4
      wk = dppmax<0x118, 0xf>(wk);   // row_shr:8
      wk = dppmax<0x142, 0xa>(wk);   // row_bcast:15 -> rows 1,3
      wk = dppmax<0x143, 0xc>(wk);   // row_bcast:31 -> rows 2,3
      u32 wlo = (u32)__builtin_amdgcn_readlane((int)(u32)wk, 63);
      u32 whi = (u32)__builtin_amdgcn_readlane((int)(u32)(wk >> 32), 63);
      u64 wmax = ((u64)whi << 32) | wlo;
      if (ckey == wmax) {            // unique owner lane (keys unique via sidx)
        // export winner (x,y,z): x via 5-level cndmask tree over own regs
        // (J = own best point; valid even for stale-key inactive lanes),
        // y,z via own-cell LDS read. All on-chip.
        int J = (int)(ckey & 31u);
        bool b4 = (J & 16) != 0, b3 = (J & 8) != 0, b2 = (J & 4) != 0,
             b1 = (J & 2) != 0, b0 = (J & 1) != 0;
#define SA(I, IP) float e##I = b4 ? x##IP : x##I;
        SA(0,16) SA(1,17) SA(2,18) SA(3,19) SA(4,20) SA(5,21) SA(6,22) SA(7,23)
        SA(8,24) SA(9,25) SA(10,26) SA(11,27) SA(12,28) SA(13,29) SA(14,30) SA(15,31)
#undef SA
#define SB(I, IP) float f##I = b3 ? e##IP : e##I;
        SB(0,8) SB(1,9) SB(2,10) SB(3,11) SB(4,12) SB(5,13) SB(6,14) SB(7,15)
#undef SB
#define SC(I, IP) float g##I = b2 ? f##IP : f##I;
        SC(0,4) SC(1,5) SC(2,6) SC(3,7)
#undef SC
        float h0 = b1 ? g2 : g0, h1 = b1 ? g3 : g1;
        float xw = b0 ? h1 : h0;
        float2 yzw = s_yz[J * FPS_T + t];
        s_wkey[p][wv] = wmax;
        s_wc[p][wv] = make_float4(xw, yzw.x, yzw.y, 0.f);
      }
    } else {
      // whole wave pruned: forward previous parity's winner entry. Single
      // writer per slot (this wave); [1-p] written at k-1, next overwrite at
      // k+1 -> always separated by the barrier below. No race.
      if ((t & 63) == 0) {
        s_wkey[p][wv] = s_wkey[1 - p][wv];
        s_wc[p][wv] = s_wc[1 - p][wv];
      }
    }
    __syncthreads();

    // ---- all waves redundantly reduce the 8 wave keys (row_ror, period-8)
    u64 gk = s_wkey[p][t & 7];
    gk = dppmax<0x121, 0xf>(gk);   // row_ror:1
    gk = dppmax<0x122, 0xf>(gk);   // row_ror:2
    gk = dppmax<0x124, 0xf>(gk);   // row_ror:4
    u32 glo = (u32)__builtin_amdgcn_readfirstlane((int)(u32)gk);
    u32 ghi = (u32)__builtin_amdgcn_readfirstlane((int)(u32)(gk >> 32));
    u64 gmax = ((u64)ghi << 32) | glo;
    int sidx = (int)(gmax & 16383u);
    if (t == 0) idx_out[k + 1] = 16383 - (int)((gmax >> 14) & 16383u);
    // next center: one b128 broadcast LDS read (no global, no cell math)
    float4 c = s_wc[p][sidx >> 11];     // wave owns 64 thr x 32 pts = 2048 pts
    cx = c.x; cy = c.y; cz = c.z;
  }
}

// ======================= zero the tail rows [N_S, N_PTS) =======================
__global__ void zero_tail(float4* __restrict__ outv, int count) {
  int i = blockIdx.x * blockDim.x + threadIdx.x;
  if (i < count) outv[i] = make_float4(0.f, 0.f, 0.f, 0.f);
}

// ======================= kNN: 8-way split + exact lex merge =======================
#define KNN_T  256   // 32 centers x 8 splits
#define KTILE  1024

__global__ __launch_bounds__(KNN_T) void knn_kernel(const float* __restrict__ pos,
                                                    const int* __restrict__ fps_idx,
                                                    int* __restrict__ src_out,
                                                    int* __restrict__ valid_out) {
  __shared__ float sx[KTILE], sy[KTILE], sz[KTILE];
  __shared__ float spd[32][8][NB];
  __shared__ int   spi[32][8][NB];
  const int t = threadIdx.x;
  const int sp = t >> 5;
  const int cl = t & 31;
  const int i = blockIdx.x * 32 + cl;
  const int ci = fps_idx[i];
  const float cx = pos[3 * ci], cy = pos[3 * ci + 1], cz = pos[3 * ci + 2];
  float nd[NB]; int ni[NB];
#pragma unroll
  for (int q = 0; q < NB; ++q) { nd[q] = 3.402823466e38f; ni[q] = 0x7fffffff; }

  for (int base = 0; base < N_PTS; base += KTILE) {
    __syncthreads();
    for (int j = t; j < KTILE; j += KNN_T) {
      int pnt = base + j;
      sx[j] = pos[3 * pnt]; sy[j] = pos[3 * pnt + 1]; sz[j] = pos[3 * pnt + 2];
    }
    __syncthreads();
    for (int j = sp; j < KTILE; j += 8) {
      float dx = __fsub_rn(cx, sx[j]);
      float dy = __fsub_rn(cy, sy[j]);
      float dz = __fsub_rn(cz, sz[j]);
      float d2 = __fadd_rn(__fadd_rn(__fmul_rn(dx, dx), __fmul_rn(dy, dy)), __fmul_rn(dz, dz));
      if (d2 < nd[NB - 1]) {
        float cd = d2; int cp = base + j;
#pragma unroll
        for (int q = 0; q < NB; ++q) {
          bool sw = (cd < nd[q]) || (cd == nd[q] && cp < ni[q]);
          if (sw) { float td = nd[q]; int tp = ni[q]; nd[q] = cd; ni[q] = cp; cd = td; cp = tp; }
        }
      }
    }
  }
#pragma unroll
  for (int q = 0; q < NB; ++q) { spd[cl][sp][q] = nd[q]; spi[cl][sp][q] = ni[q]; }
  __syncthreads();
  if (sp == 0) {
    int cur[8];
#pragma unroll
    for (int s = 0; s < 8; ++s) cur[s] = 0;
    int vb = 0;
    for (int q = 0; q < NB; ++q) {
      float bd = 3.402823466e38f; int bi = 0x7fffffff; int bsl = 0;
#pragma unroll
      for (int s = 0; s < 8; ++s) {
        float d = spd[cl][s][cur[s]]; int id = spi[cl][s][cur[s]];
        if (d < bd || (d == bd && id < bi)) { bd = d; bi = id; bsl = s; }
      }
#pragma unroll
      for (int s = 0; s < 8; ++s) cur[s] += (s == bsl) ? 1 : 0;
      src_out[i * NB + q] = bi;
      if (bd <= R2) vb |= (1 << q);
    }
    valid_out[i] = vb;
  }
}

// ======================= MLP + masked max-pool =======================
#define MLP_T 128

__global__ __launch_bounds__(MLP_T) void mlp_kernel(const float* __restrict__ pos,
                                                    const int* __restrict__ src,
                                                    const int* __restrict__ valid,
                                                    const float* __restrict__ W1,
                                                    const float* __restrict__ b1,
                                                    const float* __restrict__ W2,
                                                    const float* __restrict__ b2,
                                                    float* __restrict__ out) {
  __shared__ float sW2[CHID * COUT];
  __shared__ float sW1[3 * CHID];
  __shared__ float sb1[CHID];
  __shared__ float sh1[NB][CHID];
  __shared__ float srel[NB][3];
  __shared__ int   svalid;
  const int t = threadIdx.x;
  const int i = blockIdx.x;

  for (int e = t; e < CHID * COUT; e += MLP_T) sW2[e] = W2[e];
  for (int e = t; e < 3 * CHID; e += MLP_T) sW1[e] = W1[e];
  if (t < CHID) sb1[t] = b1[t];
  if (t < NB) {
    int s = src[i * NB + t];
    // NOTE: reference subtracts pos_i = pos[:s] (row i), NOT the sampled center
    srel[t][0] = pos[3 * s + 0] - pos[3 * i + 0];
    srel[t][1] = pos[3 * s + 1] - pos[3 * i + 1];
    srel[t][2] = pos[3 * s + 2] - pos[3 * i + 2];
  }
  if (t == 0) svalid = valid[i];
  __syncthreads();

  for (int e = t; e < NB * CHID; e += MLP_T) {
    int n = e >> 6, kk = e & 63;
    float a = sb1[kk] + srel[n][0] * sW1[kk] + srel[n][1] * sW1[64 + kk] + srel[n][2] * sW1[128 + kk];
    sh1[n][kk] = fmaxf(a, 0.0f);
  }
  __syncthreads();

  const int vmask = svalid;
  const float bb = b2[t];
  float m = 0.0f;
  bool any = false;
  for (int n = 0; n < NB; ++n) {
    if (vmask & (1 << n)) {
      float acc = bb;
      for (int kk = 0; kk < CHID; ++kk) acc += sh1[n][kk] * sW2[kk * COUT + t];
      m = any ? fmaxf(m, acc) : acc;
      any = true;
    }
  }
  out[i * COUT + t] = any ? m : 0.0f;
}

// ======================= launch =======================
extern "C" void kernel_launch(void* const* d_in, const int* in_sizes, int n_in,
                              void* d_out, int out_size, void* d_ws, size_t ws_size,
                              hipStream_t stream) {
  (void)in_sizes; (void)n_in; (void)out_size; (void)ws_size;
  const float* pos = (const float*)d_in[0];
  const float* W1 = (const float*)d_in[2];
  const float* b1 = (const float*)d_in[3];
  const float* W2 = (const float*)d_in[4];
  const float* b2 = (const float*)d_in[5];
  float* out = (float*)d_out;

  char* ws = (char*)d_ws;
  int*   idx   = (int*)ws;                 ws += (size_t)N_S * 4;          // 32 KB
  int*   src   = (int*)ws;                 ws += (size_t)N_S * NB * 4;     // 320 KB
  int*   valid = (int*)ws;                 ws += (size_t)N_S * 4;          // 32 KB
  float* xs    = (float*)ws;               ws += (size_t)N_PTS * 4;        // 64 KB
  float* ys    = (float*)ws;               ws += (size_t)N_PTS * 4;
  float* zs    = (float*)ws;               ws += (size_t)N_PTS * 4;
  int*   oid   = (int*)ws;                 ws += (size_t)N_PTS * 4;
  // sort temporaries alias the src region (sort completes before knn writes src)
  int* cellid = src;                 // N_PTS ints = 64 KB  (src region is 320 KB)
  int* hist   = src + N_PTS;         // NCELL ints = 16 KB
  int* basebuf= src + N_PTS + NCELL; // NCELL ints = 16 KB

  zero_hist<<<NCELL / 256, 256, 0, stream>>>(hist);
  cell_kernel<<<N_PTS / 256, 256, 0, stream>>>(pos, cellid, hist);
  scan_kernel<<<1, 1024, 0, stream>>>(hist, basebuf);
  scatter_kernel<<<N_PTS / 256, 256, 0, stream>>>(pos, cellid, basebuf, xs, ys, zs, oid);
  fps_kernel<<<1, FPS_T, 0, stream>>>(pos, xs, ys, zs, oid, idx);
  {
    int count = (N_PTS - N_S) * COUT / 4;
    zero_tail<<<(count + 255) / 256, 256, 0, stream>>>((float4*)(out + (size_t)N_S * COUT), count);
  }
  knn_kernel<<<N_S / 32, KNN_T, 0, stream>>>(pos, idx, src, valid);
  mlp_kernel<<<N_S, MLP_T, 0, stream>>>(pos, src, valid, W1, b1, W2, b2, out);
}

// Round 18
// 10044.599 us; speedup vs baseline: 1.6498x; 1.6498x over previous
//
#include <hip/hip_runtime.h>

typedef unsigned int u32;
typedef unsigned long long u64;

#define N_PTS 16384
#define N_S   8192
#define NB    10
#define CHID  64
#define COUT  128
#define R2    0.0625f
#define NCELL 4096

// ======================= sort: morton counting sort =======================
__global__ void zero_hist(int* __restrict__ hist) {
  hist[blockIdx.x * 256 + threadIdx.x] = 0;
}

__device__ __forceinline__ u32 spread3(u32 v) {  // 4 bits -> every 3rd bit
  return (v & 1u) | ((v & 2u) << 2) | ((v & 4u) << 4) | ((v & 8u) << 6);
}

__global__ void cell_kernel(const float* __restrict__ pos, int* __restrict__ cellid,
                            int* __restrict__ hist) {
  int i = blockIdx.x * 256 + threadIdx.x;
  float x = pos[3 * i], y = pos[3 * i + 1], z = pos[3 * i + 2];
  u32 ix = (u32)(x * 16.0f); if (ix > 15u) ix = 15u;
  u32 iy = (u32)(y * 16.0f); if (iy > 15u) iy = 15u;
  u32 iz = (u32)(z * 16.0f); if (iz > 15u) iz = 15u;
  u32 c = spread3(ix) | (spread3(iy) << 1) | (spread3(iz) << 2);
  cellid[i] = (int)c;
  atomicAdd(&hist[c], 1);
}

__global__ __launch_bounds__(1024) void scan_kernel(const int* __restrict__ hist,
                                                    int* __restrict__ base) {
  __shared__ int sp[1024];
  int t = threadIdx.x;
  int h0 = hist[4 * t], h1 = hist[4 * t + 1], h2 = hist[4 * t + 2], h3 = hist[4 * t + 3];
  int s = h0 + h1 + h2 + h3;
  int acc = s;
  sp[t] = s;
  __syncthreads();
  for (int off = 1; off < 1024; off <<= 1) {
    int v = (t >= off) ? sp[t - off] : 0;
    __syncthreads();
    acc += v;
    sp[t] = acc;
    __syncthreads();
  }
  int excl = acc - s;
  base[4 * t + 0] = excl;
  base[4 * t + 1] = excl + h0;
  base[4 * t + 2] = excl + h0 + h1;
  base[4 * t + 3] = excl + h0 + h1 + h2;
}

__global__ void scatter_kernel(const float* __restrict__ pos, const int* __restrict__ cellid,
                               int* __restrict__ base, float* __restrict__ xs,
                               float* __restrict__ ys, float* __restrict__ zs,
                               int* __restrict__ oid) {
  int i = blockIdx.x * 256 + threadIdx.x;
  int c = cellid[i];
  int d = atomicAdd(&base[c], 1);
  xs[d] = pos[3 * i]; ys[d] = pos[3 * i + 1]; zs[d] = pos[3 * i + 2];
  oid[d] = i;
}

// ======================= FPS: R16 (best verified: 9.13 ms) ======================
// R17 post-mortem: 512thr/32ppt zero-memory variant regressed 2x (2 waves/SIMD
// halves latency hiding; body doubled on the straggler wave) AND disproved the
// R16 FETCH theory (134 MB persists with a zero-global loop -> it's a noise
// floor; R16's body x-loads are L2-hits). R16 structure: 1024thr/16ppt, md in
// regs + f64-max accumulators, y/z interleaved LDS b64, packed bbox LDS,
// 1-barrier parity exchange, all-wave redundant block reduce.
#define FPS_T 1024
#define PPT   16

#define PT_LIST(OP) OP(0) OP(1) OP(2) OP(3) OP(4) OP(5) OP(6) OP(7) \
                    OP(8) OP(9) OP(10) OP(11) OP(12) OP(13) OP(14) OP(15)
// OP(G, J0,J1,J2,J3, PA,PB): float4 group G covers points 4G..4G+3, lk pairs PA,PB
#define G4_LIST(OP) OP(0,0,1,2,3,0,1)   OP(1,4,5,6,7,2,3) \
                    OP(2,8,9,10,11,4,5) OP(3,12,13,14,15,6,7)
// OP(PA, Jeven, Jodd)
#define PAIR_LIST(OP) OP(0,0,1) OP(1,2,3) OP(2,4,5) OP(3,6,7) \
                      OP(4,8,9) OP(5,10,11) OP(6,12,13) OP(7,14,15)

// u64 max via positive-double max (keys < 2^60 -> exponent never all-ones, no
// NaN/inf patterns; positive doubles order == bit order).
__device__ __forceinline__ u64 u64fmax(u64 a, u64 b) {
  double ad = __longlong_as_double((long long)a);
  double bd = __longlong_as_double((long long)b);
  return (u64)(long long)__double_as_longlong(fmax(ad, bd));
}

template <int CTRL, int RM>
__device__ __forceinline__ u64 dppmax(u64 cur) {
  int slo = __builtin_amdgcn_update_dpp(0, (int)(u32)cur, CTRL, RM, 0xf, false);
  int shi = __builtin_amdgcn_update_dpp(0, (int)(u32)(cur >> 32), CTRL, RM, 0xf, false);
  u64 o = ((u64)(u32)shi << 32) | (u32)slo;
  return u64fmax(o, cur);
}

__global__ __launch_bounds__(FPS_T, 4)
void fps_kernel(const float* __restrict__ pos,
                const float* __restrict__ xs,
                const float* __restrict__ ys,
                const float* __restrict__ zs,
                const int* __restrict__ oidv,
                int* __restrict__ idx_out) {
  __shared__ float2 s_yz[PPT * FPS_T];   // [j][t] interleaved (y,z): 128 KB
  __shared__ float4 s_bb4[FPS_T];        // (bnx,bxx,bny,bxy): 16 KB
  __shared__ float2 s_bbz[FPS_T];        // (bnz,bxz): 8 KB
  __shared__ u64    s_wkey[2][16];       // parity double-buffer
  const int t = threadIdx.x;
  const int wv = t >> 6;
  const int base0 = t * PPT;
  const float4* __restrict__ xv = (const float4*)(xs + base0);
  const float4* __restrict__ yv = (const float4*)(ys + base0);
  const float4* __restrict__ zv = (const float4*)(zs + base0);
  const int4*   __restrict__ ov = (const int4*)(oidv + base0);

  // ---- per-point register state: md only (+ packed tie keys); x from L2.
#define DECLP(J) float md##J;
  PT_LIST(DECLP)
#undef DECLP
#define DECLK(PA, JE, JO) u32 lkp##PA;
  PAIR_LIST(DECLK)
#undef DECLK

  {
    float bnx = 3.4e38f, bxx = -3.4e38f, bny = 3.4e38f, bxy = -3.4e38f,
          bnz = 3.4e38f, bxz = -3.4e38f;
#define INIT4(G, J0, J1, J2, J3, PA, PB) { \
    float4 vx = xv[G], vy = yv[G], vz = zv[G]; int4 vo = ov[G]; \
    md##J0 = 3.402823466e38f; md##J1 = 3.402823466e38f; \
    md##J2 = 3.402823466e38f; md##J3 = 3.402823466e38f; \
    s_yz[J0 * FPS_T + t] = make_float2(vy.x, vz.x); \
    s_yz[J1 * FPS_T + t] = make_float2(vy.y, vz.y); \
    s_yz[J2 * FPS_T + t] = make_float2(vy.z, vz.z); \
    s_yz[J3 * FPS_T + t] = make_float2(vy.w, vz.w); \
    lkp##PA = (16383u - (u32)vo.x) | ((16383u - (u32)vo.y) << 16); \
    lkp##PB = (16383u - (u32)vo.z) | ((16383u - (u32)vo.w) << 16); \
    bnx = fminf(bnx, fminf(fminf(vx.x, vx.y), fminf(vx.z, vx.w))); \
    bxx = fmaxf(bxx, fmaxf(fmaxf(vx.x, vx.y), fmaxf(vx.z, vx.w))); \
    bny = fminf(bny, fminf(fminf(vy.x, vy.y), fminf(vy.z, vy.w))); \
    bxy = fmaxf(bxy, fmaxf(fmaxf(vy.x, vy.y), fmaxf(vy.z, vy.w))); \
    bnz = fminf(bnz, fminf(fminf(vz.x, vz.y), fminf(vz.z, vz.w))); \
    bxz = fmaxf(bxz, fmaxf(fmaxf(vz.x, vz.y), fmaxf(vz.z, vz.w))); }
    G4_LIST(INIT4)
#undef INIT4
    s_bb4[t] = make_float4(bnx, bxx, bny, bxy);
    s_bbz[t] = make_float2(bnz, bxz);
  }

  // key = md_bits<<28 | (16383-oid)<<14 | sidx (60 bits). md >= 0 -> float order
  // == bit order. Lex max == numpy argmax (max md, tie -> min oid); sidx trails.
  u64 ckey = 0;
  float cmaxf = 3.402823466e38f;        // forces all-active first iteration
  float cx = pos[0], cy = pos[1], cz = pos[2];
  if (t == 0) idx_out[0] = 0;
  __syncthreads();

  for (int k = 0; k < N_S - 1; ++k) {
    // ---- prune: bbox lower bound vs chunk max-min-dist. Skip-safe: if
    // 0.99*lb2 >= cmaxf no md in this chunk can decrease (1% margin >> fp32
    // rounding of 3-term sums) -> chunk state exactly unchanged.
    float4 bb = s_bb4[t];
    float2 bz = s_bbz[t];
    float dxl = fmaxf(fmaxf(bb.x - cx, cx - bb.y), 0.0f);
    float dyl = fmaxf(fmaxf(bb.z - cy, cy - bb.w), 0.0f);
    float dzl = fmaxf(fmaxf(bz.x - cz, cz - bz.y), 0.0f);
    float lb2 = dxl * dxl + dyl * dyl + dzl * dzl;
    bool act = (0.99f * lb2 < cmaxf);
    const int p = k & 1;

    if (__ballot(act)) {
      if (act) {
        u64 bkA = 0, bkB = 0;   // even/odd accumulators: halves the dep chain
        // exact numpy arithmetic: per-op rounding, no FMA contraction.
        // x from global xs (64 KB, L1/L2-resident); y,z one b64 LDS read each.
#define UPD1(J, PX, LKE, ACC) { \
        float2 yz = s_yz[J * FPS_T + t]; \
        float dx = __fsub_rn(PX, cx); \
        float dy = __fsub_rn(yz.x, cy); \
        float dz = __fsub_rn(yz.y, cz); \
        float d2 = __fadd_rn(__fadd_rn(__fmul_rn(dx, dx), __fmul_rn(dy, dy)), __fmul_rn(dz, dz)); \
        float m = fminf(md##J, d2); md##J = m; \
        u32 mb = __float_as_uint(m); \
        u64 kj = ((u64)(mb >> 4) << 32) | ((mb << 28) | ((LKE) << 14) | (u32)(base0 + J)); \
        ACC = u64fmax(ACC, kj); }
#define UPDG(G, J0, J1, J2, J3, PA, PB) { \
        float4 vx = xv[G]; \
        UPD1(J0, vx.x, (lkp##PA & 0xffffu), bkA) \
        UPD1(J1, vx.y, (lkp##PA >> 16), bkB) \
        UPD1(J2, vx.z, (lkp##PB & 0xffffu), bkA) \
        UPD1(J3, vx.w, (lkp##PB >> 16), bkB) }
        G4_LIST(UPDG)
#undef UPDG
#undef UPD1
        ckey = u64fmax(bkA, bkB);
        cmaxf = __uint_as_float((u32)(ckey >> 28));
      }
      // wave64 max via DPP (row_shr scan + row broadcasts): lane 63 = wave max.
      // Inactive lanes carry their old (still-valid) ckey.
      u64 wk = ckey;
      wk = dppmax<0x111, 0xf>(wk);   // row_shr:1
      wk = dppmax<0x112, 0xf>(wk);   // row_shr:2
      wk = dppmax<0x114, 0xf>(wk);   // row_shr:4
      wk = dppmax<0x118, 0xf>(wk);   // row_shr:8
      wk = dppmax<0x142, 0xa>(wk);   // row_bcast:15 -> rows 1,3
      wk = dppmax<0x143, 0xc>(wk);   // row_bcast:31 -> rows 2,3
      u32 wlo = (u32)__builtin_amdgcn_readlane((int)(u32)wk, 63);
      u32 whi = (u32)__builtin_amdgcn_readlane((int)(u32)(wk >> 32), 63);
      if ((t & 63) == 0) s_wkey[p][wv] = ((u64)whi << 32) | wlo;
    } else {
      // whole wave pruned: forward previous parity's winner entry. Single
      // writer per slot (this wave); [1-p] written at k-1, next overwrite at
      // k+1 -> always separated by the barrier below. No race.
      if ((t & 63) == 0) s_wkey[p][wv] = s_wkey[1 - p][wv];
    }
    __syncthreads();

    // ---- all waves redundantly reduce the 16 wave keys (row_ror, period-16)
    u64 gk = s_wkey[p][t & 15];
    gk = dppmax<0x121, 0xf>(gk);   // row_ror:1
    gk = dppmax<0x122, 0xf>(gk);   // row_ror:2
    gk = dppmax<0x124, 0xf>(gk);   // row_ror:4
    gk = dppmax<0x128, 0xf>(gk);   // row_ror:8
    u32 glo = (u32)__builtin_amdgcn_readfirstlane((int)(u32)gk);
    u32 ghi = (u32)__builtin_amdgcn_readfirstlane((int)(u32)(gk >> 32));
    u64 gmax = ((u64)ghi << 32) | glo;
    int sidx = (int)(gmax & 16383u);      // SGPR (from readfirstlane chain)
    if (t == 0) idx_out[k + 1] = 16383 - (int)((gmax >> 14) & 16383u);
    // next center: cx via scalar load from L1/L2-resident xs (sidx uniform);
    // cy,cz from the point's LDS cell (uniform broadcast b64 read).
    int cell = (sidx & (PPT - 1)) * FPS_T + (sidx >> 4);
    cx = xs[sidx];
    float2 yz = s_yz[cell];
    cy = yz.x;
    cz = yz.y;
  }
}

// ======================= zero the tail rows [N_S, N_PTS) =======================
__global__ void zero_tail(float4* __restrict__ outv, int count) {
  int i = blockIdx.x * blockDim.x + threadIdx.x;
  if (i < count) outv[i] = make_float4(0.f, 0.f, 0.f, 0.f);
}

// ======================= kNN: 8-way split + exact lex merge =======================
#define KNN_T  256   // 32 centers x 8 splits
#define KTILE  1024

__global__ __launch_bounds__(KNN_T) void knn_kernel(const float* __restrict__ pos,
                                                    const int* __restrict__ fps_idx,
                                                    int* __restrict__ src_out,
                                                    int* __restrict__ valid_out) {
  __shared__ float sx[KTILE], sy[KTILE], sz[KTILE];
  __shared__ float spd[32][8][NB];
  __shared__ int   spi[32][8][NB];
  const int t = threadIdx.x;
  const int sp = t >> 5;
  const int cl = t & 31;
  const int i = blockIdx.x * 32 + cl;
  const int ci = fps_idx[i];
  const float cx = pos[3 * ci], cy = pos[3 * ci + 1], cz = pos[3 * ci + 2];
  float nd[NB]; int ni[NB];
#pragma unroll
  for (int q = 0; q < NB; ++q) { nd[q] = 3.402823466e38f; ni[q] = 0x7fffffff; }

  for (int base = 0; base < N_PTS; base += KTILE) {
    __syncthreads();
    for (int j = t; j < KTILE; j += KNN_T) {
      int pnt = base + j;
      sx[j] = pos[3 * pnt]; sy[j] = pos[3 * pnt + 1]; sz[j] = pos[3 * pnt + 2];
    }
    __syncthreads();
    for (int j = sp; j < KTILE; j += 8) {
      float dx = __fsub_rn(cx, sx[j]);
      float dy = __fsub_rn(cy, sy[j]);
      float dz = __fsub_rn(cz, sz[j]);
      float d2 = __fadd_rn(__fadd_rn(__fmul_rn(dx, dx), __fmul_rn(dy, dy)), __fmul_rn(dz, dz));
      if (d2 < nd[NB - 1]) {
        float cd = d2; int cp = base + j;
#pragma unroll
        for (int q = 0; q < NB; ++q) {
          bool sw = (cd < nd[q]) || (cd == nd[q] && cp < ni[q]);
          if (sw) { float td = nd[q]; int tp = ni[q]; nd[q] = cd; ni[q] = cp; cd = td; cp = tp; }
        }
      }
    }
  }
#pragma unroll
  for (int q = 0; q < NB; ++q) { spd[cl][sp][q] = nd[q]; spi[cl][sp][q] = ni[q]; }
  __syncthreads();
  if (sp == 0) {
    int cur[8];
#pragma unroll
    for (int s = 0; s < 8; ++s) cur[s] = 0;
    int vb = 0;
    for (int q = 0; q < NB; ++q) {
      float bd = 3.402823466e38f; int bi = 0x7fffffff; int bsl = 0;
#pragma unroll
      for (int s = 0; s < 8; ++s) {
        float d = spd[cl][s][cur[s]]; int id = spi[cl][s][cur[s]];
        if (d < bd || (d == bd && id < bi)) { bd = d; bi = id; bsl = s; }
      }
#pragma unroll
      for (int s = 0; s < 8; ++s) cur[s] += (s == bsl) ? 1 : 0;
      src_out[i * NB + q] = bi;
      if (bd <= R2) vb |= (1 << q);
    }
    valid_out[i] = vb;
  }
}

// ======================= MLP + masked max-pool =======================
#define MLP_T 128

__global__ __launch_bounds__(MLP_T) void mlp_kernel(const float* __restrict__ pos,
                                                    const int* __restrict__ src,
                                                    const int* __restrict__ valid,
                                                    const float* __restrict__ W1,
                                                    const float* __restrict__ b1,
                                                    const float* __restrict__ W2,
                                                    const float* __restrict__ b2,
                                                    float* __restrict__ out) {
  __shared__ float sW2[CHID * COUT];
  __shared__ float sW1[3 * CHID];
  __shared__ float sb1[CHID];
  __shared__ float sh1[NB][CHID];
  __shared__ float srel[NB][3];
  __shared__ int   svalid;
  const int t = threadIdx.x;
  const int i = blockIdx.x;

  for (int e = t; e < CHID * COUT; e += MLP_T) sW2[e] = W2[e];
  for (int e = t; e < 3 * CHID; e += MLP_T) sW1[e] = W1[e];
  if (t < CHID) sb1[t] = b1[t];
  if (t < NB) {
    int s = src[i * NB + t];
    // NOTE: reference subtracts pos_i = pos[:s] (row i), NOT the sampled center
    srel[t][0] = pos[3 * s + 0] - pos[3 * i + 0];
    srel[t][1] = pos[3 * s + 1] - pos[3 * i + 1];
    srel[t][2] = pos[3 * s + 2] - pos[3 * i + 2];
  }
  if (t == 0) svalid = valid[i];
  __syncthreads();

  for (int e = t; e < NB * CHID; e += MLP_T) {
    int n = e >> 6, kk = e & 63;
    float a = sb1[kk] + srel[n][0] * sW1[kk] + srel[n][1] * sW1[64 + kk] + srel[n][2] * sW1[128 + kk];
    sh1[n][kk] = fmaxf(a, 0.0f);
  }
  __syncthreads();

  const int vmask = svalid;
  const float bb = b2[t];
  float m = 0.0f;
  bool any = false;
  for (int n = 0; n < NB; ++n) {
    if (vmask & (1 << n)) {
      float acc = bb;
      for (int kk = 0; kk < CHID; ++kk) acc += sh1[n][kk] * sW2[kk * COUT + t];
      m = any ? fmaxf(m, acc) : acc;
      any = true;
    }
  }
  out[i * COUT + t] = any ? m : 0.0f;
}

// ======================= launch =======================
extern "C" void kernel_launch(void* const* d_in, const int* in_sizes, int n_in,
                              void* d_out, int out_size, void* d_ws, size_t ws_size,
                              hipStream_t stream) {
  (void)in_sizes; (void)n_in; (void)out_size; (void)ws_size;
  const float* pos = (const float*)d_in[0];
  const float* W1 = (const float*)d_in[2];
  const float* b1 = (const float*)d_in[3];
  const float* W2 = (const float*)d_in[4];
  const float* b2 = (const float*)d_in[5];
  float* out = (float*)d_out;

  char* ws = (char*)d_ws;
  int*   idx   = (int*)ws;                 ws += (size_t)N_S * 4;          // 32 KB
  int*   src   = (int*)ws;                 ws += (size_t)N_S * NB * 4;     // 320 KB
  int*   valid = (int*)ws;                 ws += (size_t)N_S * 4;          // 32 KB
  float* xs    = (float*)ws;               ws += (size_t)N_PTS * 4;        // 64 KB
  float* ys    = (float*)ws;               ws += (size_t)N_PTS * 4;
  float* zs    = (float*)ws;               ws += (size_t)N_PTS * 4;
  int*   oid   = (int*)ws;                 ws += (size_t)N_PTS * 4;
  // sort temporaries alias the src region (sort completes before knn writes src)
  int* cellid = src;                 // N_PTS ints = 64 KB  (src region is 320 KB)
  int* hist   = src + N_PTS;         // NCELL ints = 16 KB
  int* basebuf= src + N_PTS + NCELL; // NCELL ints = 16 KB

  zero_hist<<<NCELL / 256, 256, 0, stream>>>(hist);
  cell_kernel<<<N_PTS / 256, 256, 0, stream>>>(pos, cellid, hist);
  scan_kernel<<<1, 1024, 0, stream>>>(hist, basebuf);
  scatter_kernel<<<N_PTS / 256, 256, 0, stream>>>(pos, cellid, basebuf, xs, ys, zs, oid);
  fps_kernel<<<1, FPS_T, 0, stream>>>(pos, xs, ys, zs, oid, idx);
  {
    int count = (N_PTS - N_S) * COUT / 4;
    zero_tail<<<(count + 255) / 256, 256, 0, stream>>>((float4*)(out + (size_t)N_S * COUT), count);
  }
  knn_kernel<<<N_S / 32, KNN_T, 0, stream>>>(pos, idx, src, valid);
  mlp_kernel<<<N_S, MLP_T, 0, stream>>>(pos, src, valid, W1, b1, W2, b2, out);
}